// Round 1
// baseline (351.733 us; speedup 1.0000x reference)
//
#include <hip/hip_runtime.h>

typedef __attribute__((ext_vector_type(4))) float f32x4;
typedef __attribute__((ext_vector_type(8))) short bfrag; // 8 x bf16 in 4 VGPRs

#define NROWS 65536
#define NCH 256
#define KP 448
#define BN_EPS 1e-5f

__device__ __forceinline__ unsigned short cvt_bf16(float f){
  unsigned u = __float_as_uint(f);
  u += 0x7FFFu + ((u >> 16) & 1u);           // round-to-nearest-even
  return (unsigned short)(u >> 16);
}
__device__ __forceinline__ float bf16tof(unsigned short h){
  return __uint_as_float(((unsigned)h) << 16);
}

// ---- K0: split W1 (pad K 440->448) and W2 into bf16 hi/lo pairs ----
__global__ void k_prep(const float* __restrict__ W1, const float* __restrict__ W2,
                       unsigned short* __restrict__ W1hi, unsigned short* __restrict__ W1lo,
                       unsigned short* __restrict__ W2hi, unsigned short* __restrict__ W2lo){
  int t = blockIdx.x * 256 + threadIdx.x;
  if (t < 256 * KP){
    int c = t / KP, k = t % KP;
    float v = (k < 440) ? W1[c * 440 + k] : 0.f;
    unsigned short hi = cvt_bf16(v);
    W1hi[t] = hi;
    W1lo[t] = cvt_bf16(v - bf16tof(hi));
  }
  if (t < 64 * 256){
    float v = W2[t];
    unsigned short hi = cvt_bf16(v);
    W2hi[t] = hi;
    W2lo[t] = cvt_bf16(v - bf16tof(hi));
  }
}

// ---- K1: fused gather + GEMM1 (split-bf16 MFMA) + h1 + block stats ----
// block = 256 thr = 4 waves; wave w owns rows [blk*64 + w*16, +16), all 256 chans.
// A-frag: lane l supplies x[row = l&15][k = (l>>4)*8 + e] -> one 32B gather per K-step.
__global__ __launch_bounds__(256, 2) void k_gemm1(
    const int* __restrict__ state, const int* __restrict__ counts, const int* __restrict__ mp,
    const float* __restrict__ embed, const float* __restrict__ stab, const float* __restrict__ ctab,
    const unsigned short* __restrict__ W1hi, const unsigned short* __restrict__ W1lo,
    const float* __restrict__ b1,
    float* __restrict__ h1, float* __restrict__ partials)
{
  const int tid = threadIdx.x;
  const int w  = tid >> 6;
  const int l  = tid & 63;
  const int lr = l & 15;
  const int g  = l >> 4;
  const int rowbase = blockIdx.x * 64 + w * 16;
  const int arow = rowbase + lr;

  const int st = state[arow] * 32;
  const int ct = counts[arow] * 16;
  const int mpbase = arow * 49;

  // hoist mp index loads (prefetch the gather chain's first level)
  int midx[14];
  #pragma unroll
  for (int s = 0; s < 14; ++s){
    int kk = s * 32 + g * 8;
    int m = (kk - 48) >> 3;
    midx[s] = (kk >= 48 && kk < 440) ? ((mp[mpbase + m] & 0xFFFFFF) * 8) : -1;
  }

  f32x4 acc[16];
  #pragma unroll
  for (int i = 0; i < 16; ++i) acc[i] = (f32x4){0.f, 0.f, 0.f, 0.f};

  #pragma unroll
  for (int s = 0; s < 14; ++s){
    const int kk = s * 32 + g * 8;
    f32x4 va, vb;
    if (kk < 32){
      va = *(const f32x4*)(stab + st + kk);
      vb = *(const f32x4*)(stab + st + kk + 4);
    } else if (kk < 48){
      va = *(const f32x4*)(ctab + ct + (kk - 32));
      vb = *(const f32x4*)(ctab + ct + (kk - 32) + 4);
    } else if (midx[s] >= 0){
      va = *(const f32x4*)(embed + midx[s]);
      vb = *(const f32x4*)(embed + midx[s] + 4);
    } else {
      va = (f32x4){0.f,0.f,0.f,0.f}; vb = va;
    }

    bfrag ahi, alo;
    #pragma unroll
    for (int e = 0; e < 4; ++e){
      unsigned short h0 = cvt_bf16(va[e]);
      ahi[e]     = (short)h0;
      alo[e]     = (short)cvt_bf16(va[e] - bf16tof(h0));
      unsigned short h1b = cvt_bf16(vb[e]);
      ahi[4 + e] = (short)h1b;
      alo[4 + e] = (short)cvt_bf16(vb[e] - bf16tof(h1b));
    }

    const unsigned short* bh = W1hi + lr * KP + kk;
    const unsigned short* bl = W1lo + lr * KP + kk;
    #pragma unroll
    for (int c = 0; c < 16; ++c){
      bfrag bhi = *(const bfrag*)(bh + c * 16 * KP);
      bfrag blo = *(const bfrag*)(bl + c * 16 * KP);
      acc[c] = __builtin_amdgcn_mfma_f32_16x16x32_bf16(ahi, bhi, acc[c], 0, 0, 0);
      acc[c] = __builtin_amdgcn_mfma_f32_16x16x32_bf16(alo, bhi, acc[c], 0, 0, 0);
      acc[c] = __builtin_amdgcn_mfma_f32_16x16x32_bf16(ahi, blo, acc[c], 0, 0, 0);
    }
  }

  // epilogue: bias, write h1 (D layout: row=(l>>4)*4+e, col=l&15), stats
  __shared__ float wsum[4][256];
  __shared__ float wsq[4][256];

  #pragma unroll
  for (int c = 0; c < 16; ++c){
    int j = c * 16 + lr;
    float bb = b1[j];
    float s = 0.f, q = 0.f;
    #pragma unroll
    for (int e = 0; e < 4; ++e){
      float h = acc[c][e] + bb;
      s += h; q += h * h;
      h1[(rowbase + g * 4 + e) * NCH + j] = h;
    }
    s += __shfl_xor(s, 16);  s += __shfl_xor(s, 32);
    q += __shfl_xor(q, 16);  q += __shfl_xor(q, 32);
    if (g == 0){ wsum[w][j] = s; wsq[w][j] = q; }
  }
  __syncthreads();
  if (tid < 256){
    float s = wsum[0][tid] + wsum[1][tid] + wsum[2][tid] + wsum[3][tid];
    float q = wsq[0][tid]  + wsq[1][tid]  + wsq[2][tid]  + wsq[3][tid];
    partials[blockIdx.x * 512 + tid]       = s;
    partials[blockIdx.x * 512 + 256 + tid] = q;
  }
}

// ---- K2: reduce partials -> scale/shift per channel ----
__global__ __launch_bounds__(256) void k_stats(const float* __restrict__ partials,
    const float* __restrict__ gamma, const float* __restrict__ beta,
    float* __restrict__ ss){
  int j = blockIdx.x;
  int t = threadIdx.x;
  float s = 0.f, q = 0.f;
  for (int b = t; b < 1024; b += 256){
    s += partials[b * 512 + j];
    q += partials[b * 512 + 256 + j];
  }
  __shared__ float rs[256], rq[256];
  rs[t] = s; rq[t] = q;
  __syncthreads();
  for (int off = 128; off > 0; off >>= 1){
    if (t < off){ rs[t] += rs[t + off]; rq[t] += rq[t + off]; }
    __syncthreads();
  }
  if (t == 0){
    float mu   = rs[0] * (1.f / 65536.f);
    float var  = rq[0] * (1.f / 65536.f) - mu * mu;
    float rsig = rsqrtf(var + BN_EPS);
    float sc   = gamma[j] * rsig;
    ss[j]       = sc;
    ss[256 + j] = beta[j] - mu * sc;
  }
}

// ---- K3: BN + GEMM2(split-bf16 MFMA) + ReLU + GEMM3 + ReLU + GEMM4 ----
__global__ __launch_bounds__(256, 2) void k_tail(
    const float* __restrict__ h1, const float* __restrict__ ss,
    const unsigned short* __restrict__ W2hi, const unsigned short* __restrict__ W2lo,
    const float* __restrict__ b2, const float* __restrict__ W3, const float* __restrict__ b3,
    const float* __restrict__ W4, const float* __restrict__ b4,
    float* __restrict__ out)
{
  const int tid = threadIdx.x;
  const int w  = tid >> 6;
  const int l  = tid & 63;
  const int lr = l & 15;
  const int g  = l >> 4;
  const int rowbase = blockIdx.x * 64 + w * 16;

  f32x4 acc[4];
  #pragma unroll
  for (int i = 0; i < 4; ++i) acc[i] = (f32x4){0.f, 0.f, 0.f, 0.f};

  #pragma unroll
  for (int s = 0; s < 8; ++s){
    const int kk = s * 32 + g * 8;
    f32x4 va = *(const f32x4*)(h1 + (rowbase + lr) * 256 + kk);
    f32x4 vb = *(const f32x4*)(h1 + (rowbase + lr) * 256 + kk + 4);
    f32x4 sa = *(const f32x4*)(ss + kk);
    f32x4 sb = *(const f32x4*)(ss + kk + 4);
    f32x4 ta = *(const f32x4*)(ss + 256 + kk);
    f32x4 tb = *(const f32x4*)(ss + 256 + kk + 4);

    bfrag ahi, alo;
    #pragma unroll
    for (int e = 0; e < 4; ++e){
      float x0 = va[e] * sa[e] + ta[e];
      unsigned short h0 = cvt_bf16(x0);
      ahi[e]     = (short)h0;
      alo[e]     = (short)cvt_bf16(x0 - bf16tof(h0));
      float x1 = vb[e] * sb[e] + tb[e];
      unsigned short h1b = cvt_bf16(x1);
      ahi[4 + e] = (short)h1b;
      alo[4 + e] = (short)cvt_bf16(x1 - bf16tof(h1b));
    }

    const unsigned short* bh = W2hi + lr * 256 + kk;
    const unsigned short* bl = W2lo + lr * 256 + kk;
    #pragma unroll
    for (int c = 0; c < 4; ++c){
      bfrag bhi = *(const bfrag*)(bh + c * 16 * 256);
      bfrag blo = *(const bfrag*)(bl + c * 16 * 256);
      acc[c] = __builtin_amdgcn_mfma_f32_16x16x32_bf16(ahi, bhi, acc[c], 0, 0, 0);
      acc[c] = __builtin_amdgcn_mfma_f32_16x16x32_bf16(alo, bhi, acc[c], 0, 0, 0);
      acc[c] = __builtin_amdgcn_mfma_f32_16x16x32_bf16(ahi, blo, acc[c], 0, 0, 0);
    }
  }

  // h2 = relu(acc + b2) -> LDS (pad 65 to kill bank conflicts)
  __shared__ float h2l[4][16][65];
  #pragma unroll
  for (int c = 0; c < 4; ++c){
    int j = c * 16 + lr;
    float bb = b2[j];
    #pragma unroll
    for (int e = 0; e < 4; ++e){
      float h = acc[c][e] + bb;
      h2l[w][g * 4 + e][j] = h > 0.f ? h : 0.f;
    }
  }
  __syncthreads();

  // GEMM3: lane computes h3[row=lr][jj=g*4+t], 64-deep dots from LDS
  float a3[4];
  #pragma unroll
  for (int t3 = 0; t3 < 4; ++t3) a3[t3] = b3[g * 4 + t3];
  #pragma unroll 4
  for (int k = 0; k < 64; ++k){
    float hv = h2l[w][lr][k];
    #pragma unroll
    for (int t3 = 0; t3 < 4; ++t3) a3[t3] += hv * W3[(g * 4 + t3) * 64 + k];
  }

  // GEMM4: relu then dot with W4; reduce the 4 lane-groups
  float p = 0.f;
  #pragma unroll
  for (int t3 = 0; t3 < 4; ++t3){
    float h = a3[t3] > 0.f ? a3[t3] : 0.f;
    p += h * W4[g * 4 + t3];
  }
  p += __shfl_xor(p, 16);
  p += __shfl_xor(p, 32);
  if (l < 16) out[rowbase + lr] = p + b4[0];
}

extern "C" void kernel_launch(void* const* d_in, const int* in_sizes, int n_in,
                              void* d_out, int out_size, void* d_ws, size_t ws_size,
                              hipStream_t stream){
  const int*   state = (const int*)d_in[0];
  const int*   counts= (const int*)d_in[1];
  const int*   mp    = (const int*)d_in[2];
  const float* embed = (const float*)d_in[3];
  const float* stab  = (const float*)d_in[4];
  const float* ctab  = (const float*)d_in[5];
  const float* W1    = (const float*)d_in[6];
  const float* b1    = (const float*)d_in[7];
  const float* gamma = (const float*)d_in[8];
  const float* beta  = (const float*)d_in[9];
  const float* W2    = (const float*)d_in[10];
  const float* b2    = (const float*)d_in[11];
  const float* W3    = (const float*)d_in[12];
  const float* b3    = (const float*)d_in[13];
  const float* W4    = (const float*)d_in[14];
  const float* b4    = (const float*)d_in[15];
  float* out = (float*)d_out;

  char* ws = (char*)d_ws;
  float* h1            = (float*)(ws);                       // 64 MiB
  float* partials      = (float*)(ws + 67108864);            // 2 MiB
  float* ss            = (float*)(ws + 69206016);            // 2 KiB
  unsigned short* W1hi = (unsigned short*)(ws + 69208064);   // 224 KiB
  unsigned short* W1lo = (unsigned short*)(ws + 69437440);   // 224 KiB
  unsigned short* W2hi = (unsigned short*)(ws + 69666816);   // 32 KiB
  unsigned short* W2lo = (unsigned short*)(ws + 69699584);   // 32 KiB

  k_prep <<<448, 256, 0, stream>>>(W1, W2, W1hi, W1lo, W2hi, W2lo);
  k_gemm1<<<1024, 256, 0, stream>>>(state, counts, mp, embed, stab, ctab,
                                    W1hi, W1lo, b1, h1, partials);
  k_stats<<<256, 256, 0, stream>>>(partials, gamma, beta, ss);
  k_tail <<<1024, 256, 0, stream>>>(h1, ss, W2hi, W2lo, b2, W3, b3, W4, b4, out);
}

// Round 2
// 152.414 us; speedup vs baseline: 2.3077x; 2.3077x over previous
//
#include <hip/hip_runtime.h>

typedef __attribute__((ext_vector_type(4))) float f32x4;
typedef __attribute__((ext_vector_type(8))) short bfrag; // 8 x bf16 in 4 VGPRs

#define NCH 256
#define BN_EPS 1e-5f

__device__ __forceinline__ unsigned short cvt_bf16(float f){
  unsigned u = __float_as_uint(f);
  u += 0x7FFFu + ((u >> 16) & 1u);           // round-to-nearest-even
  return (unsigned short)(u >> 16);
}
__device__ __forceinline__ float bf16tof(unsigned short h){
  return __uint_as_float(((unsigned)h) << 16);
}
__device__ __forceinline__ void split2(const f32x4 va, const f32x4 vb, bfrag& hi, bfrag& lo){
  #pragma unroll
  for (int e = 0; e < 4; ++e){
    unsigned short h0 = cvt_bf16(va[e]);
    hi[e]   = (short)h0;
    lo[e]   = (short)cvt_bf16(va[e] - bf16tof(h0));
    unsigned short h1b = cvt_bf16(vb[e]);
    hi[4+e] = (short)h1b;
    lo[4+e] = (short)cvt_bf16(vb[e] - bf16tof(h1b));
  }
}

#define GLOAD_LDS16(gp, lp) \
  __builtin_amdgcn_global_load_lds((const __attribute__((address_space(1))) unsigned*)(gp), \
                                   (__attribute__((address_space(3))) unsigned*)(lp), 16, 0, 0)

// ---- K0: pack W1 into per-step fragment layout W1p[s][half][c][l][e]; split W2 hi/lo ----
// W1p step s slice = contiguous 32 KiB; lane l's ds_read_b128 hits bytes l*16 (conflict-free).
__global__ void k_prep(const float* __restrict__ W1, const float* __restrict__ W2,
                       unsigned short* __restrict__ W1p,
                       unsigned short* __restrict__ W2hi, unsigned short* __restrict__ W2lo){
  int t = blockIdx.x * 256 + threadIdx.x;
  if (t < 14 * 8192){
    int e = t & 7, l = (t >> 3) & 63, c = (t >> 9) & 15, s = t >> 13;
    int chan = c * 16 + (l & 15);
    int k = s * 32 + (l >> 4) * 8 + e;
    float v = (k < 440) ? W1[chan * 440 + k] : 0.f;
    unsigned short hi = cvt_bf16(v);
    W1p[s * 16384 + c * 512 + l * 8 + e]        = hi;
    W1p[s * 16384 + 8192 + c * 512 + l * 8 + e] = cvt_bf16(v - bf16tof(hi));
  }
  if (t < 64 * 256){
    float v = W2[t];
    unsigned short hi = cvt_bf16(v);
    W2hi[t] = hi;
    W2lo[t] = cvt_bf16(v - bf16tof(hi));
  }
}

__device__ __forceinline__ void stage_w(const char* __restrict__ wsrc, short* smem,
                                        int S, int BUF, int w, int l){
  #pragma unroll
  for (int r = 0; r < 8; ++r)
    GLOAD_LDS16(wsrc + S * 32768 + (w * 8 + r) * 1024 + l * 16,
                (char*)smem + BUF * 32768 + (w * 8 + r) * 1024);
}

// ---- K1: fused gather + GEMM1 (split-bf16 MFMA, W staged in LDS) + h1 + block stats ----
// 512 blocks x 256 thr (4 waves); block covers 128 rows; wave w: 32 rows (2 tiles of 16).
__global__ __launch_bounds__(256, 2) void k_gemm1(
    const int* __restrict__ state, const int* __restrict__ counts, const int* __restrict__ mp,
    const float* __restrict__ embed, const float* __restrict__ stab, const float* __restrict__ ctab,
    const unsigned short* __restrict__ W1p, const float* __restrict__ b1,
    float* __restrict__ h1, float* __restrict__ partials)
{
  __shared__ __align__(16) short smem[2 * 16384];   // 64 KiB: double-buffered W step slice
  __shared__ float wsum[4][256];
  __shared__ float wsq[4][256];

  const int tid = threadIdx.x;
  const int w  = tid >> 6;
  const int l  = tid & 63;
  const int lr = l & 15;
  const int g  = l >> 4;
  const int rowbase = blockIdx.x * 128 + w * 32;
  const int arow0 = rowbase + lr;
  const int arow1 = rowbase + 16 + lr;

  const int st0 = state[arow0] * 32, st1 = state[arow1] * 32;
  const int ct0 = counts[arow0] * 16, ct1 = counts[arow1] * 16;
  const long mpb0 = (long)arow0 * 49, mpb1 = (long)arow1 * 49;
  const char* wsrc = (const char*)W1p;

  int   mpr[2][2];
  f32x4 xva[2][2], xvb[2][2];

  // mp-index load for step S (clamped; unused lanes load harmless valid rows)
  #define ISSUE_MP(S) do {                                          \
    int m_ = 4 * (S) + g - 6;                                       \
    m_ = m_ < 0 ? 0 : (m_ > 48 ? 48 : m_);                          \
    mpr[(S)&1][0] = (mp[mpb0 + m_] & 0xFFFFFF) << 3;                \
    mpr[(S)&1][1] = (mp[mpb1 + m_] & 0xFFFFFF) << 3;                \
  } while(0)

  // x gather-issue for step S (2 row-tiles, 32B each)
  #define ISSUE_X(S) do {                                            \
    const float *p0_, *p1_;                                          \
    if ((S) == 0){ p0_ = stab + st0 + g * 8; p1_ = stab + st1 + g * 8; } \
    else if ((S) == 1){                                              \
      p0_ = (g < 2) ? (ctab + ct0 + g * 8) : (embed + mpr[1][0]);    \
      p1_ = (g < 2) ? (ctab + ct1 + g * 8) : (embed + mpr[1][1]);    \
    } else { p0_ = embed + mpr[(S)&1][0]; p1_ = embed + mpr[(S)&1][1]; } \
    xva[(S)&1][0] = *(const f32x4*)p0_;  xvb[(S)&1][0] = *(const f32x4*)(p0_ + 4); \
    xva[(S)&1][1] = *(const f32x4*)p1_;  xvb[(S)&1][1] = *(const f32x4*)(p1_ + 4); \
  } while(0)

  f32x4 acc0[16], acc1[16];
  #pragma unroll
  for (int i = 0; i < 16; ++i){ acc0[i] = (f32x4){0.f,0.f,0.f,0.f}; acc1[i] = acc0[i]; }

  // ---- prologue: mp(1), stage(0)->buf0, then x(0) (machine-ordered after stage) ----
  ISSUE_MP(1);
  stage_w(wsrc, smem, 0, 0, w, l);
  asm volatile("" ::: "memory");
  __builtin_amdgcn_sched_barrier(0);
  ISSUE_X(0);

  bfrag ahi0, alo0, ahi1, alo1;

  #pragma unroll
  for (int s = 0; s < 14; ++s){
    // [A] stage next W slice first (older than next x loads -> auto-drained by cvt(s+1))
    if (s < 13) stage_w(wsrc, smem, s + 1, (s + 1) & 1, w, l);
    asm volatile("" ::: "memory");
    __builtin_amdgcn_sched_barrier(0);

    // [B] mp two ahead; convert x(s) (compiler vmcnt wait here also retires stage(s));
    //     then issue x(s+1)
    if (s < 12) ISSUE_MP(s + 2);
    {
      f32x4 va0 = xva[s & 1][0], vb0 = xvb[s & 1][0];
      f32x4 va1 = xva[s & 1][1], vb1 = xvb[s & 1][1];
      if (s == 13 && g == 3){                      // K-pad 440..447 -> zeros
        va0 = (f32x4){0.f,0.f,0.f,0.f}; vb0 = va0; va1 = va0; vb1 = va0;
      }
      split2(va0, vb0, ahi0, alo0);
      split2(va1, vb1, ahi1, alo1);
    }
    if (s < 13) ISSUE_X(s + 1);

    // [C] barrier: every wave has retired its own stage(s) writes (vmcnt wait above)
    __builtin_amdgcn_sched_barrier(0);
    asm volatile("s_barrier" ::: "memory");

    // [D] MFMA on buf[s&1]: conflict-free ds_read_b128, 96 MFMA/step
    {
      const char* base = (const char*)smem + (s & 1) * 32768 + l * 16;
      #pragma unroll
      for (int c = 0; c < 16; ++c){
        const bfrag bhi = *(const bfrag*)(base + c * 1024);
        const bfrag blo = *(const bfrag*)(base + 16384 + c * 1024);
        acc0[c] = __builtin_amdgcn_mfma_f32_16x16x32_bf16(ahi0, bhi, acc0[c], 0, 0, 0);
        acc0[c] = __builtin_amdgcn_mfma_f32_16x16x32_bf16(alo0, bhi, acc0[c], 0, 0, 0);
        acc0[c] = __builtin_amdgcn_mfma_f32_16x16x32_bf16(ahi0, blo, acc0[c], 0, 0, 0);
        acc1[c] = __builtin_amdgcn_mfma_f32_16x16x32_bf16(ahi1, bhi, acc1[c], 0, 0, 0);
        acc1[c] = __builtin_amdgcn_mfma_f32_16x16x32_bf16(alo1, bhi, acc1[c], 0, 0, 0);
        acc1[c] = __builtin_amdgcn_mfma_f32_16x16x32_bf16(ahi1, blo, acc1[c], 0, 0, 0);
      }
    }

    // [E] barrier: buf[s&1] free for stage(s+2) next iteration
    asm volatile("s_barrier" ::: "memory");
  }
  #undef ISSUE_MP
  #undef ISSUE_X

  // ---- epilogue: bias, h1 write, batch stats ----
  #pragma unroll
  for (int c = 0; c < 16; ++c){
    const int j = c * 16 + lr;
    const float bb = b1[j];
    float s = 0.f, q = 0.f;
    #pragma unroll
    for (int e = 0; e < 4; ++e){
      float h = acc0[c][e] + bb;
      s += h; q += h * h;
      h1[(rowbase + g * 4 + e) * NCH + j] = h;
    }
    #pragma unroll
    for (int e = 0; e < 4; ++e){
      float h = acc1[c][e] + bb;
      s += h; q += h * h;
      h1[(rowbase + 16 + g * 4 + e) * NCH + j] = h;
    }
    s += __shfl_xor(s, 16);  s += __shfl_xor(s, 32);
    q += __shfl_xor(q, 16);  q += __shfl_xor(q, 32);
    if (g == 0){ wsum[w][j] = s; wsq[w][j] = q; }
  }
  __syncthreads();
  {
    float s = wsum[0][tid] + wsum[1][tid] + wsum[2][tid] + wsum[3][tid];
    float q = wsq[0][tid]  + wsq[1][tid]  + wsq[2][tid]  + wsq[3][tid];
    partials[blockIdx.x * 512 + tid]       = s;
    partials[blockIdx.x * 512 + 256 + tid] = q;
  }
}

// ---- K2: reduce partials -> scale/shift per channel ----
__global__ __launch_bounds__(256) void k_stats(const float* __restrict__ partials,
    const float* __restrict__ gamma, const float* __restrict__ beta,
    float* __restrict__ ss){
  int j = blockIdx.x;
  int t = threadIdx.x;
  float s = 0.f, q = 0.f;
  for (int b = t; b < 512; b += 256){
    s += partials[b * 512 + j];
    q += partials[b * 512 + 256 + j];
  }
  __shared__ float rs[256], rq[256];
  rs[t] = s; rq[t] = q;
  __syncthreads();
  for (int off = 128; off > 0; off >>= 1){
    if (t < off){ rs[t] += rs[t + off]; rq[t] += rq[t + off]; }
    __syncthreads();
  }
  if (t == 0){
    float mu   = rs[0] * (1.f / 65536.f);
    float var  = rq[0] * (1.f / 65536.f) - mu * mu;
    float rsig = rsqrtf(var + BN_EPS);
    float sc   = gamma[j] * rsig;
    ss[j]       = sc;
    ss[256 + j] = beta[j] - mu * sc;
  }
}

// ---- K3: BN + GEMM2(split-bf16 MFMA) + ReLU + GEMM3 + ReLU + GEMM4 ----
__global__ __launch_bounds__(256, 2) void k_tail(
    const float* __restrict__ h1, const float* __restrict__ ss,
    const unsigned short* __restrict__ W2hi, const unsigned short* __restrict__ W2lo,
    const float* __restrict__ b2, const float* __restrict__ W3, const float* __restrict__ b3,
    const float* __restrict__ W4, const float* __restrict__ b4,
    float* __restrict__ out)
{
  const int tid = threadIdx.x;
  const int w  = tid >> 6;
  const int l  = tid & 63;
  const int lr = l & 15;
  const int g  = l >> 4;
  const int rowbase = blockIdx.x * 64 + w * 16;

  f32x4 acc[4];
  #pragma unroll
  for (int i = 0; i < 4; ++i) acc[i] = (f32x4){0.f, 0.f, 0.f, 0.f};

  #pragma unroll
  for (int s = 0; s < 8; ++s){
    const int kk = s * 32 + g * 8;
    f32x4 va = *(const f32x4*)(h1 + (rowbase + lr) * 256 + kk);
    f32x4 vb = *(const f32x4*)(h1 + (rowbase + lr) * 256 + kk + 4);
    f32x4 sa = *(const f32x4*)(ss + kk);
    f32x4 sb = *(const f32x4*)(ss + kk + 4);
    f32x4 ta = *(const f32x4*)(ss + 256 + kk);
    f32x4 tb = *(const f32x4*)(ss + 256 + kk + 4);

    bfrag ahi, alo;
    #pragma unroll
    for (int e = 0; e < 4; ++e){
      float x0 = va[e] * sa[e] + ta[e];
      unsigned short h0 = cvt_bf16(x0);
      ahi[e]     = (short)h0;
      alo[e]     = (short)cvt_bf16(x0 - bf16tof(h0));
      float x1 = vb[e] * sb[e] + tb[e];
      unsigned short h1b = cvt_bf16(x1);
      ahi[4 + e] = (short)h1b;
      alo[4 + e] = (short)cvt_bf16(x1 - bf16tof(h1b));
    }

    const unsigned short* bh = W2hi + lr * 256 + kk;
    const unsigned short* bl = W2lo + lr * 256 + kk;
    #pragma unroll
    for (int c = 0; c < 4; ++c){
      bfrag bhi = *(const bfrag*)(bh + c * 16 * 256);
      bfrag blo = *(const bfrag*)(bl + c * 16 * 256);
      acc[c] = __builtin_amdgcn_mfma_f32_16x16x32_bf16(ahi, bhi, acc[c], 0, 0, 0);
      acc[c] = __builtin_amdgcn_mfma_f32_16x16x32_bf16(alo, bhi, acc[c], 0, 0, 0);
      acc[c] = __builtin_amdgcn_mfma_f32_16x16x32_bf16(ahi, blo, acc[c], 0, 0, 0);
    }
  }

  __shared__ float h2l[4][16][65];
  #pragma unroll
  for (int c = 0; c < 4; ++c){
    int j = c * 16 + lr;
    float bb = b2[j];
    #pragma unroll
    for (int e = 0; e < 4; ++e){
      float h = acc[c][e] + bb;
      h2l[w][g * 4 + e][j] = h > 0.f ? h : 0.f;
    }
  }
  __syncthreads();

  float a3[4];
  #pragma unroll
  for (int t3 = 0; t3 < 4; ++t3) a3[t3] = b3[g * 4 + t3];
  #pragma unroll 4
  for (int k = 0; k < 64; ++k){
    float hv = h2l[w][lr][k];
    #pragma unroll
    for (int t3 = 0; t3 < 4; ++t3) a3[t3] += hv * W3[(g * 4 + t3) * 64 + k];
  }

  float p = 0.f;
  #pragma unroll
  for (int t3 = 0; t3 < 4; ++t3){
    float h = a3[t3] > 0.f ? a3[t3] : 0.f;
    p += h * W4[g * 4 + t3];
  }
  p += __shfl_xor(p, 16);
  p += __shfl_xor(p, 32);
  if (l < 16) out[rowbase + lr] = p + b4[0];
}

extern "C" void kernel_launch(void* const* d_in, const int* in_sizes, int n_in,
                              void* d_out, int out_size, void* d_ws, size_t ws_size,
                              hipStream_t stream){
  const int*   state = (const int*)d_in[0];
  const int*   counts= (const int*)d_in[1];
  const int*   mp    = (const int*)d_in[2];
  const float* embed = (const float*)d_in[3];
  const float* stab  = (const float*)d_in[4];
  const float* ctab  = (const float*)d_in[5];
  const float* W1    = (const float*)d_in[6];
  const float* b1    = (const float*)d_in[7];
  const float* gamma = (const float*)d_in[8];
  const float* beta  = (const float*)d_in[9];
  const float* W2    = (const float*)d_in[10];
  const float* b2    = (const float*)d_in[11];
  const float* W3    = (const float*)d_in[12];
  const float* b3    = (const float*)d_in[13];
  const float* W4    = (const float*)d_in[14];
  const float* b4    = (const float*)d_in[15];
  float* out = (float*)d_out;

  char* ws = (char*)d_ws;
  float* h1            = (float*)(ws);                       // 64 MiB
  float* partials      = (float*)(ws + 67108864);            // 1 MiB
  float* ss            = (float*)(ws + 68157440);            // 2 KiB
  unsigned short* W1p  = (unsigned short*)(ws + 68159488);   // 448 KiB packed
  unsigned short* W2hi = (unsigned short*)(ws + 68618240);   // 32 KiB
  unsigned short* W2lo = (unsigned short*)(ws + 68651008);   // 32 KiB

  k_prep <<<448, 256, 0, stream>>>(W1, W2, W1p, W2hi, W2lo);
  k_gemm1<<<512, 256, 0, stream>>>(state, counts, mp, embed, stab, ctab,
                                   W1p, b1, h1, partials);
  k_stats<<<256, 256, 0, stream>>>(partials, gamma, beta, ss);
  k_tail <<<1024, 256, 0, stream>>>(h1, ss, W2hi, W2lo, b2, W3, b3, W4, b4, out);
}

// Round 3
// 120.979 us; speedup vs baseline: 2.9074x; 1.2598x over previous
//
#include <hip/hip_runtime.h>

typedef __attribute__((ext_vector_type(4))) float f32x4;
typedef __attribute__((ext_vector_type(8))) short bfrag; // 8 x bf16 in 4 VGPRs

#define NCH 256
#define BN_EPS 1e-5f

__device__ __forceinline__ unsigned short cvt_bf16(float f){
  unsigned u = __float_as_uint(f);
  u += 0x7FFFu + ((u >> 16) & 1u);           // round-to-nearest-even
  return (unsigned short)(u >> 16);
}
__device__ __forceinline__ float bf16tof(unsigned short h){
  return __uint_as_float(((unsigned)h) << 16);
}
__device__ __forceinline__ void split2(const f32x4 va, const f32x4 vb, bfrag& hi, bfrag& lo){
  #pragma unroll
  for (int e = 0; e < 4; ++e){
    unsigned short h0 = cvt_bf16(va[e]);
    hi[e]   = (short)h0;
    lo[e]   = (short)cvt_bf16(va[e] - bf16tof(h0));
    unsigned short h1b = cvt_bf16(vb[e]);
    hi[4+e] = (short)h1b;
    lo[4+e] = (short)cvt_bf16(vb[e] - bf16tof(h1b));
  }
}

#define GLOAD_LDS16(gp, lp) \
  __builtin_amdgcn_global_load_lds((const __attribute__((address_space(1))) unsigned*)(gp), \
                                   (__attribute__((address_space(3))) unsigned*)(lp), 16, 0, 0)

// ---- K0: pack W1 (hi-only, K padded 440->448) and W2 (hi-only) into MFMA fragment order ----
// layout [step][c][lane][e]: lane l reads bytes l*16 of a 1KiB c-chunk -> conflict-free b128.
__global__ void k_prep(const float* __restrict__ W1, const float* __restrict__ W2,
                       unsigned short* __restrict__ W1p, unsigned short* __restrict__ W2p){
  int t = blockIdx.x * 256 + threadIdx.x;
  if (t < 14 * 8192){
    int e = t & 7, l = (t >> 3) & 63, c = (t >> 9) & 15, s = t >> 13;
    int chan = c * 16 + (l & 15);
    int k = s * 32 + (l >> 4) * 8 + e;
    float v = (k < 440) ? W1[chan * 440 + k] : 0.f;
    W1p[s * 8192 + c * 512 + l * 8 + e] = cvt_bf16(v);
  }
  if (t < 16384){
    int e = t & 7, l = (t >> 3) & 63, c = (t >> 9) & 3, s = t >> 11;
    int chan = c * 16 + (l & 15);
    int k = s * 32 + (l >> 4) * 8 + e;
    W2p[s * 2048 + c * 512 + l * 8 + e] = cvt_bf16(W2[chan * 256 + k]);
  }
}

__device__ __forceinline__ void stage_w(const char* __restrict__ wsrc, short* smem,
                                        int S, int BUF, int w, int l){
  #pragma unroll
  for (int r = 0; r < 4; ++r)
    GLOAD_LDS16(wsrc + S * 16384 + (w * 4 + r) * 1024 + l * 16,
                (char*)smem + BUF * 16384 + (w * 4 + r) * 1024);
}

// ---- K1: gather + GEMM1 (2-pass split-bf16 MFMA) + h1(bf16) + batch-stat atomics ----
// 512 blocks x 256 thr (4 waves); block covers 128 rows; wave w: 32 rows (2 tiles of 16).
__global__ __launch_bounds__(256, 2) void k_gemm1(
    const int* __restrict__ state, const int* __restrict__ counts, const int* __restrict__ mp,
    const float* __restrict__ embed, const float* __restrict__ stab, const float* __restrict__ ctab,
    const unsigned short* __restrict__ W1p, const float* __restrict__ b1,
    unsigned short* __restrict__ h1b, float* __restrict__ gsum)
{
  __shared__ __align__(16) short smem[2 * 8192];     // 32 KiB: double-buffered W step slice
  __shared__ __align__(16) int   mp_lds[6272];       // 24.5 KiB: block's mp[128][49]
  __shared__ float wsum[4][256];
  __shared__ float wsq[4][256];

  const int tid = threadIdx.x;
  const int w  = tid >> 6;
  const int l  = tid & 63;
  const int lr = l & 15;
  const int g  = l >> 4;
  const int rowbase = blockIdx.x * 128 + w * 32;
  const int arow0 = rowbase + lr;
  const int arow1 = rowbase + 16 + lr;

  const int st0 = state[arow0] * 32, st1 = state[arow1] * 32;
  const int ct0 = counts[arow0] * 16, ct1 = counts[arow1] * 16;
  const char* wsrc = (const char*)W1p;

  // ---- stage this block's mp slice into LDS (coalesced, 25088 B = 1568 x 16B) ----
  {
    const char* mpsrc = (const char*)(mp + (size_t)blockIdx.x * 6272);
    #pragma unroll
    for (int it = 0; it < 7; ++it){
      int idx = it * 256 + tid;
      if (idx < 1568)
        GLOAD_LDS16(mpsrc + idx * 16, (char*)mp_lds + idx * 16);
    }
  }

  f32x4 xva[2][2], xvb[2][2];
  f32x4 acc0[16], acc1[16];
  #pragma unroll
  for (int i = 0; i < 16; ++i){ acc0[i] = (f32x4){0.f,0.f,0.f,0.f}; acc1[i] = acc0[i]; }

  // ---- prologue: stage W(0), x(0) from state table; full drain; barrier ----
  stage_w(wsrc, smem, 0, 0, w, l);
  {
    const float* p0 = stab + st0 + g * 8;
    const float* p1 = stab + st1 + g * 8;
    xva[0][0] = *(const f32x4*)p0;  xvb[0][0] = *(const f32x4*)(p0 + 4);
    xva[0][1] = *(const f32x4*)p1;  xvb[0][1] = *(const f32x4*)(p1 + 4);
  }
  asm volatile("s_waitcnt vmcnt(0)" ::: "memory");
  __builtin_amdgcn_sched_barrier(0);
  __builtin_amdgcn_s_barrier();      // mp_lds globally valid from here

  bfrag ahi0, alo0, ahi1, alo1;

  #pragma unroll
  for (int s = 0; s < 14; ++s){
    // [A] stage next W slice (stays in flight across the barrier)
    if (s < 13) stage_w(wsrc, smem, s + 1, (s + 1) & 1, w, l);
    asm volatile("" ::: "memory");
    __builtin_amdgcn_sched_barrier(0);

    // [B] convert x(s) (compiler's vmcnt wait for x(s) also retires older stage(s));
    //     then issue x(s+1) using mp indices read from LDS
    {
      f32x4 va0 = xva[s & 1][0], vb0 = xvb[s & 1][0];
      f32x4 va1 = xva[s & 1][1], vb1 = xvb[s & 1][1];
      if (s == 13 && g == 3){                      // K-pad 440..447 -> zeros
        va0 = (f32x4){0.f,0.f,0.f,0.f}; vb0 = va0; va1 = va0; vb1 = va0;
      }
      split2(va0, vb0, ahi0, alo0);
      split2(va1, vb1, ahi1, alo1);
    }
    if (s < 13){
      const int S = s + 1;
      int m = 4 * S + g - 6;
      m = m < 0 ? 0 : (m > 48 ? 48 : m);
      const float *p0, *p1;
      if (S == 1 && g < 2){
        p0 = ctab + ct0 + g * 8;
        p1 = ctab + ct1 + g * 8;
      } else {
        p0 = embed + ((mp_lds[(w * 32 + lr) * 49 + m]      & 0xFFFFFF) << 3);
        p1 = embed + ((mp_lds[(w * 32 + 16 + lr) * 49 + m] & 0xFFFFFF) << 3);
      }
      xva[S & 1][0] = *(const f32x4*)p0;  xvb[S & 1][0] = *(const f32x4*)(p0 + 4);
      xva[S & 1][1] = *(const f32x4*)p1;  xvb[S & 1][1] = *(const f32x4*)(p1 + 4);
    }

    // [C] barrier: every wave has retired its own stage(s) writes (vmcnt wait above)
    __builtin_amdgcn_sched_barrier(0);
    __builtin_amdgcn_s_barrier();

    // [D] MFMA on buf[s&1]: 16 conflict-free ds_read_b128, 64 MFMA/step
    {
      const char* base = (const char*)smem + (s & 1) * 16384 + l * 16;
      #pragma unroll
      for (int c = 0; c < 16; ++c){
        const bfrag bhi = *(const bfrag*)(base + c * 1024);
        acc0[c] = __builtin_amdgcn_mfma_f32_16x16x32_bf16(ahi0, bhi, acc0[c], 0, 0, 0);
        acc0[c] = __builtin_amdgcn_mfma_f32_16x16x32_bf16(alo0, bhi, acc0[c], 0, 0, 0);
        acc1[c] = __builtin_amdgcn_mfma_f32_16x16x32_bf16(ahi1, bhi, acc1[c], 0, 0, 0);
        acc1[c] = __builtin_amdgcn_mfma_f32_16x16x32_bf16(alo1, bhi, acc1[c], 0, 0, 0);
      }
    }

    // [E] barrier: buf[s&1] free for stage(s+2)
    __builtin_amdgcn_s_barrier();
  }

  // ---- epilogue: bias, h1(bf16) write, batch-stat atomics ----
  #pragma unroll
  for (int c = 0; c < 16; ++c){
    const int j = c * 16 + lr;
    const float bb = b1[j];
    float s = 0.f, q = 0.f;
    #pragma unroll
    for (int e = 0; e < 4; ++e){
      float h = acc0[c][e] + bb;
      s += h; q += h * h;
      h1b[(rowbase + g * 4 + e) * NCH + j] = cvt_bf16(h);
    }
    #pragma unroll
    for (int e = 0; e < 4; ++e){
      float h = acc1[c][e] + bb;
      s += h; q += h * h;
      h1b[(rowbase + 16 + g * 4 + e) * NCH + j] = cvt_bf16(h);
    }
    s += __shfl_xor(s, 16);  s += __shfl_xor(s, 32);
    q += __shfl_xor(q, 16);  q += __shfl_xor(q, 32);
    if (g == 0){ wsum[w][j] = s; wsq[w][j] = q; }
  }
  __syncthreads();
  {
    float s = wsum[0][tid] + wsum[1][tid] + wsum[2][tid] + wsum[3][tid];
    float q = wsq[0][tid]  + wsq[1][tid]  + wsq[2][tid]  + wsq[3][tid];
    atomicAdd(&gsum[tid], s);
    atomicAdd(&gsum[256 + tid], q);
  }
}

// ---- K2: BN(from gsum) + GEMM2 (2-pass MFMA, W2 in LDS) + ReLU + GEMM3 + ReLU + GEMM4 ----
__global__ __launch_bounds__(256, 3) void k_tail(
    const unsigned short* __restrict__ h1b, const float* __restrict__ gsum,
    const float* __restrict__ gamma, const float* __restrict__ beta,
    const unsigned short* __restrict__ W2p,
    const float* __restrict__ b2, const float* __restrict__ W3, const float* __restrict__ b3,
    const float* __restrict__ W4, const float* __restrict__ b4,
    float* __restrict__ out)
{
  __shared__ float ssl[512];
  __shared__ __align__(16) short w2s[16384];   // 32 KiB
  __shared__ float h2l[4][16][65];

  const int tid = threadIdx.x;
  const int w  = tid >> 6;
  const int l  = tid & 63;
  const int lr = l & 15;
  const int g  = l >> 4;
  const int rowbase = blockIdx.x * 64 + w * 16;

  // per-channel scale/shift from global sums
  {
    float su = gsum[tid & 255];
    float sq = gsum[256 + (tid & 255)];
    float mu  = su * (1.f / 65536.f);
    float var = sq * (1.f / 65536.f) - mu * mu;
    float sc  = gamma[tid & 255] * rsqrtf(var + BN_EPS);
    ssl[tid & 255]       = sc;
    ssl[256 + (tid & 255)] = beta[tid & 255] - mu * sc;
  }
  // stage W2p into LDS (32 KiB, coalesced)
  #pragma unroll
  for (int it = 0; it < 8; ++it)
    GLOAD_LDS16((const char*)W2p + (it * 256 + tid) * 16, (char*)w2s + (it * 256 + tid) * 16);
  __syncthreads();   // drains vmcnt(0) + lgkmcnt(0)

  f32x4 acc[4];
  #pragma unroll
  for (int i = 0; i < 4; ++i) acc[i] = (f32x4){0.f, 0.f, 0.f, 0.f};

  #pragma unroll
  for (int s = 0; s < 8; ++s){
    const int kk = s * 32 + g * 8;
    bfrag hv = *(const bfrag*)(h1b + (rowbase + lr) * 256 + kk);
    bfrag ahi, alo;
    #pragma unroll
    for (int e = 0; e < 8; ++e){
      float x = fmaf(bf16tof((unsigned short)hv[e]), ssl[kk + e], ssl[256 + kk + e]);
      unsigned short h0 = cvt_bf16(x);
      ahi[e] = (short)h0;
      alo[e] = (short)cvt_bf16(x - bf16tof(h0));
    }
    const char* base = (const char*)w2s + s * 4096 + l * 16;
    #pragma unroll
    for (int c = 0; c < 4; ++c){
      const bfrag bhi = *(const bfrag*)(base + c * 1024);
      acc[c] = __builtin_amdgcn_mfma_f32_16x16x32_bf16(ahi, bhi, acc[c], 0, 0, 0);
      acc[c] = __builtin_amdgcn_mfma_f32_16x16x32_bf16(alo, bhi, acc[c], 0, 0, 0);
    }
  }

  #pragma unroll
  for (int c = 0; c < 4; ++c){
    int j = c * 16 + lr;
    float bb = b2[j];
    #pragma unroll
    for (int e = 0; e < 4; ++e){
      float h = acc[c][e] + bb;
      h2l[w][g * 4 + e][j] = h > 0.f ? h : 0.f;
    }
  }
  __syncthreads();

  float a3[4];
  #pragma unroll
  for (int t3 = 0; t3 < 4; ++t3) a3[t3] = b3[g * 4 + t3];
  #pragma unroll 4
  for (int k = 0; k < 64; ++k){
    float hv = h2l[w][lr][k];
    #pragma unroll
    for (int t3 = 0; t3 < 4; ++t3) a3[t3] += hv * W3[(g * 4 + t3) * 64 + k];
  }

  float p = 0.f;
  #pragma unroll
  for (int t3 = 0; t3 < 4; ++t3){
    float h = a3[t3] > 0.f ? a3[t3] : 0.f;
    p += h * W4[g * 4 + t3];
  }
  p += __shfl_xor(p, 16);
  p += __shfl_xor(p, 32);
  if (l < 16) out[rowbase + lr] = p + b4[0];
}

extern "C" void kernel_launch(void* const* d_in, const int* in_sizes, int n_in,
                              void* d_out, int out_size, void* d_ws, size_t ws_size,
                              hipStream_t stream){
  const int*   state = (const int*)d_in[0];
  const int*   counts= (const int*)d_in[1];
  const int*   mp    = (const int*)d_in[2];
  const float* embed = (const float*)d_in[3];
  const float* stab  = (const float*)d_in[4];
  const float* ctab  = (const float*)d_in[5];
  const float* W1    = (const float*)d_in[6];
  const float* b1    = (const float*)d_in[7];
  const float* gamma = (const float*)d_in[8];
  const float* beta  = (const float*)d_in[9];
  const float* W2    = (const float*)d_in[10];
  const float* b2    = (const float*)d_in[11];
  const float* W3    = (const float*)d_in[12];
  const float* b3    = (const float*)d_in[13];
  const float* W4    = (const float*)d_in[14];
  const float* b4    = (const float*)d_in[15];
  float* out = (float*)d_out;

  char* ws = (char*)d_ws;
  unsigned short* h1bf = (unsigned short*)(ws);              // 32 MiB
  float* gsum          = (float*)(ws + 33554432);            // 2 KiB (sum|sq)
  unsigned short* W1p  = (unsigned short*)(ws + 33556480);   // 224 KiB
  unsigned short* W2p  = (unsigned short*)(ws + 33785856);   // 32 KiB

  hipMemsetAsync(gsum, 0, 2048, stream);
  k_prep <<<448, 256, 0, stream>>>(W1, W2, W1p, W2p);
  k_gemm1<<<512, 256, 0, stream>>>(state, counts, mp, embed, stab, ctab,
                                   W1p, b1, h1bf, gsum);
  k_tail <<<1024, 256, 0, stream>>>(h1bf, gsum, gamma, beta, W2p,
                                    b2, W3, b3, W4, b4, out);
}

// Round 5
// 117.874 us; speedup vs baseline: 2.9840x; 1.0263x over previous
//
#include <hip/hip_runtime.h>

typedef __attribute__((ext_vector_type(4))) float f32x4;
typedef __attribute__((ext_vector_type(8))) short bfrag; // 8 x bf16 in 4 VGPRs

#define NCH 256
#define BN_EPS 1e-5f

__device__ __forceinline__ unsigned short cvt_bf16(float f){
  unsigned u = __float_as_uint(f);
  u += 0x7FFFu + ((u >> 16) & 1u);           // round-to-nearest-even
  return (unsigned short)(u >> 16);
}
__device__ __forceinline__ float bf16tof(unsigned short h){
  return __uint_as_float(((unsigned)h) << 16);
}
__device__ __forceinline__ void split2(const f32x4 va, const f32x4 vb, bfrag& hi, bfrag& lo){
  #pragma unroll
  for (int e = 0; e < 4; ++e){
    unsigned short h0 = cvt_bf16(va[e]);
    hi[e]   = (short)h0;
    lo[e]   = (short)cvt_bf16(va[e] - bf16tof(h0));
    unsigned short h1b = cvt_bf16(vb[e]);
    hi[4+e] = (short)h1b;
    lo[4+e] = (short)cvt_bf16(vb[e] - bf16tof(h1b));
  }
}

#define GLOAD_LDS16(gp, lp) \
  __builtin_amdgcn_global_load_lds((const __attribute__((address_space(1))) unsigned*)(gp), \
                                   (__attribute__((address_space(3))) unsigned*)(lp), 16, 0, 0)

// ---- K0: pack W1 (hi-only, K 440->448) and W2 (hi-only) into MFMA fragment order;
//      zero gsum ----
__global__ void k_prep(const float* __restrict__ W1, const float* __restrict__ W2,
                       unsigned short* __restrict__ W1p, unsigned short* __restrict__ W2p,
                       float* __restrict__ gsum){
  int t = blockIdx.x * 256 + threadIdx.x;
  if (t < 14 * 8192){
    int e = t & 7, l = (t >> 3) & 63, c = (t >> 9) & 15, s = t >> 13;
    int chan = c * 16 + (l & 15);
    int k = s * 32 + (l >> 4) * 8 + e;
    float v = (k < 440) ? W1[chan * 440 + k] : 0.f;
    W1p[s * 8192 + c * 512 + l * 8 + e] = cvt_bf16(v);
  }
  if (t < 16384){
    int e = t & 7, l = (t >> 3) & 63, c = (t >> 9) & 3, s = t >> 11;
    int chan = c * 16 + (l & 15);
    int k = s * 32 + (l >> 4) * 8 + e;
    W2p[s * 2048 + c * 512 + l * 8 + e] = cvt_bf16(W2[chan * 256 + k]);
  }
  if (t < 512) gsum[t] = 0.f;
}

__device__ __forceinline__ void stage_w(const char* __restrict__ wsrc, char* smem,
                                        int S, int BUF, int w, int l){
  #pragma unroll
  for (int r = 0; r < 4; ++r)
    GLOAD_LDS16(wsrc + S * 16384 + (w * 4 + r) * 1024 + l * 16,
                smem + BUF * 16384 + (w * 4 + r) * 1024);
}

// ---- K1: gather + GEMM1 (2-pass split-bf16 MFMA, 2-step-deep gather pipeline)
//      + h1(bf16) + batch-stat atomics ----
// 512 blocks x 256 thr (4 waves); block = 128 rows; wave w: 32 rows (2 tiles of 16).
__global__ __launch_bounds__(256, 2) void k_gemm1(
    const int* __restrict__ state, const int* __restrict__ counts, const int* __restrict__ mp,
    const float* __restrict__ embed, const float* __restrict__ stab, const float* __restrict__ ctab,
    const unsigned short* __restrict__ W1p, const float* __restrict__ b1,
    unsigned short* __restrict__ h1b, float* __restrict__ gsum)
{
  __shared__ __align__(16) char smem[2 * 16384];     // 32 KiB W double-buffer
  __shared__ __align__(16) int  mp_lds[6272];        // 24.5 KiB mp[128][49]
  __shared__ float wsum[4][256];
  __shared__ float wsq[4][256];

  const int tid = threadIdx.x;
  const int w  = tid >> 6;
  const int l  = tid & 63;
  const int lr = l & 15;
  const int g  = l >> 4;
  const int rowbase = blockIdx.x * 128 + w * 32;
  const int arow0 = rowbase + lr;
  const int arow1 = rowbase + 16 + lr;

  const int st0 = state[arow0] * 32, st1 = state[arow1] * 32;
  const int ct0 = counts[arow0] * 16, ct1 = counts[arow1] * 16;
  const char* wsrc = (const char*)W1p;

  // stage this block's mp slice (coalesced 25088 B)
  {
    const char* mpsrc = (const char*)(mp + (size_t)blockIdx.x * 6272);
    #pragma unroll
    for (int it = 0; it < 7; ++it){
      int idx = it * 256 + tid;
      if (idx < 1568)
        GLOAD_LDS16(mpsrc + idx * 16, (char*)mp_lds + idx * 16);
    }
  }

  f32x4 xva[3][2], xvb[3][2];   // 3-slot ring: x(s), x(s+1), x(s+2)
  f32x4 acc0[16], acc1[16];
  #pragma unroll
  for (int i = 0; i < 16; ++i){ acc0[i] = (f32x4){0.f,0.f,0.f,0.f}; acc1[i] = acc0[i]; }

  // x gather-issue for step S into ring slot S%3 (2 row-tiles, 32B each = 4 vm loads)
  #define ISSUE_X(S) do {                                            \
    const float *p0_, *p1_;                                          \
    if ((S) == 0){ p0_ = stab + st0 + g * 8; p1_ = stab + st1 + g * 8; } \
    else if ((S) == 1 && g < 2){                                     \
      p0_ = ctab + ct0 + g * 8; p1_ = ctab + ct1 + g * 8;            \
    } else {                                                         \
      int m_ = 4 * (S) + g - 6;                                      \
      m_ = m_ < 0 ? 0 : (m_ > 48 ? 48 : m_);                         \
      p0_ = embed + ((mp_lds[(w * 32 + lr) * 49 + m_]      & 0xFFFFFF) << 3); \
      p1_ = embed + ((mp_lds[(w * 32 + 16 + lr) * 49 + m_] & 0xFFFFFF) << 3); \
    }                                                                \
    xva[(S)%3][0] = *(const f32x4*)p0_;  xvb[(S)%3][0] = *(const f32x4*)(p0_ + 4); \
    xva[(S)%3][1] = *(const f32x4*)p1_;  xvb[(S)%3][1] = *(const f32x4*)(p1_ + 4); \
  } while(0)

  // ---- prologue: mp+W(0)+x(0) issued; full drain; barrier (mp_lds valid); x(1) ----
  stage_w(wsrc, smem, 0, 0, w, l);
  ISSUE_X(0);
  asm volatile("s_waitcnt vmcnt(0)" ::: "memory");
  __builtin_amdgcn_sched_barrier(0);
  __builtin_amdgcn_s_barrier();
  ISSUE_X(1);
  asm volatile("" ::: "memory");
  __builtin_amdgcn_sched_barrier(0);

  bfrag ahi0, alo0, ahi1, alo1;

  #pragma unroll
  for (int s = 0; s < 14; ++s){
    // [A] stage W(s+1) (in flight across barriers)
    if (s < 13) stage_w(wsrc, smem, s + 1, (s + 1) & 1, w, l);
    asm volatile("" ::: "memory");
    __builtin_amdgcn_sched_barrier(0);

    // [B] consume x(s) -> frags; issue x(s+2)
    {
      f32x4 va0 = xva[s % 3][0], vb0 = xvb[s % 3][0];
      f32x4 va1 = xva[s % 3][1], vb1 = xvb[s % 3][1];
      if (s == 13 && g == 3){                      // K-pad 440..447 -> zeros
        va0 = (f32x4){0.f,0.f,0.f,0.f}; vb0 = va0; va1 = va0; vb1 = va0;
      }
      split2(va0, vb0, ahi0, alo0);
      split2(va1, vb1, ahi1, alo1);
    }
    if (s < 12) ISSUE_X(s + 2);

    // [C] retire stage(s): issue order guarantees in-order vmcnt retirement.
    // steady state: outstanding newer than stage(s) = x(s+1),stage(s+1),x(s+2) = 12
    __builtin_amdgcn_sched_barrier(0);
    if (s <= 11)      asm volatile("s_waitcnt vmcnt(12)" ::: "memory");
    else if (s == 12) asm volatile("s_waitcnt vmcnt(8)"  ::: "memory");
    else              asm volatile("s_waitcnt vmcnt(0)"  ::: "memory");
    __builtin_amdgcn_sched_barrier(0);
    __builtin_amdgcn_s_barrier();

    // [D] MFMA on buf[s&1]: 16 conflict-free ds_read_b128, 64 MFMA/step
    {
      const char* base = smem + (s & 1) * 16384 + l * 16;
      #pragma unroll
      for (int c = 0; c < 16; ++c){
        const bfrag bhi = *(const bfrag*)(base + c * 1024);
        acc0[c] = __builtin_amdgcn_mfma_f32_16x16x32_bf16(ahi0, bhi, acc0[c], 0, 0, 0);
        acc0[c] = __builtin_amdgcn_mfma_f32_16x16x32_bf16(alo0, bhi, acc0[c], 0, 0, 0);
        acc1[c] = __builtin_amdgcn_mfma_f32_16x16x32_bf16(ahi1, bhi, acc1[c], 0, 0, 0);
        acc1[c] = __builtin_amdgcn_mfma_f32_16x16x32_bf16(alo1, bhi, acc1[c], 0, 0, 0);
      }
    }

    // [E] barrier: buf[s&1] free for stage(s+2)
    __builtin_amdgcn_s_barrier();
  }
  #undef ISSUE_X

  // ---- epilogue: bias, h1(bf16) write (D: row=g*4+e, col=lr), stats -> atomics ----
  #pragma unroll
  for (int c = 0; c < 16; ++c){
    const int j = c * 16 + lr;
    const float bb = b1[j];
    float s = 0.f, q = 0.f;
    #pragma unroll
    for (int e = 0; e < 4; ++e){
      float h = acc0[c][e] + bb;
      s += h; q += h * h;
      h1b[(rowbase + g * 4 + e) * NCH + j] = cvt_bf16(h);
    }
    #pragma unroll
    for (int e = 0; e < 4; ++e){
      float h = acc1[c][e] + bb;
      s += h; q += h * h;
      h1b[(rowbase + 16 + g * 4 + e) * NCH + j] = cvt_bf16(h);
    }
    s += __shfl_xor(s, 16);  s += __shfl_xor(s, 32);
    q += __shfl_xor(q, 16);  q += __shfl_xor(q, 32);
    if (g == 0){ wsum[w][j] = s; wsq[w][j] = q; }
  }
  __syncthreads();
  {
    float s = wsum[0][tid] + wsum[1][tid] + wsum[2][tid] + wsum[3][tid];
    float q = wsq[0][tid]  + wsq[1][tid]  + wsq[2][tid]  + wsq[3][tid];
    atomicAdd(&gsum[tid], s);
    atomicAdd(&gsum[256 + tid], q);
  }
}

// ---- K2: BN(from gsum) + GEMM2 (2-pass MFMA, W2 in LDS) + ReLU + GEMM3 + ReLU + GEMM4 ----
// 512 blocks x 256 thr; block = 128 rows; wave w: 2 tiles of 16 rows (reuses staged W2).
__global__ __launch_bounds__(256, 3) void k_tail(
    const unsigned short* __restrict__ h1b, const float* __restrict__ gsum,
    const float* __restrict__ gamma, const float* __restrict__ beta,
    const unsigned short* __restrict__ W2p,
    const float* __restrict__ b2, const float* __restrict__ W3, const float* __restrict__ b3,
    const float* __restrict__ W4, const float* __restrict__ b4,
    float* __restrict__ out)
{
  __shared__ float ssl[512];
  __shared__ __align__(16) short w2s[16384];   // 32 KiB
  __shared__ float h2l[4][16][65];

  const int tid = threadIdx.x;
  const int w  = tid >> 6;
  const int l  = tid & 63;
  const int lr = l & 15;
  const int g  = l >> 4;
  const int rowbase = blockIdx.x * 128 + w * 32;

  // per-channel scale/shift from global sums
  {
    float su = gsum[tid];
    float sq = gsum[256 + tid];
    float mu  = su * (1.f / 65536.f);
    float var = sq * (1.f / 65536.f) - mu * mu;
    float sc  = gamma[tid] * rsqrtf(var + BN_EPS);
    ssl[tid]       = sc;
    ssl[256 + tid] = beta[tid] - mu * sc;
  }
  // stage W2p into LDS (32 KiB, coalesced)
  #pragma unroll
  for (int it = 0; it < 8; ++it)
    GLOAD_LDS16((const char*)W2p + (it * 256 + tid) * 16, (char*)w2s + (it * 256 + tid) * 16);
  __syncthreads();   // drains vmcnt + lgkmcnt

  const float b4v = b4[0];

  #pragma unroll
  for (int t = 0; t < 2; ++t){
    const int rowt = rowbase + t * 16;

    f32x4 acc[4];
    #pragma unroll
    for (int i = 0; i < 4; ++i) acc[i] = (f32x4){0.f, 0.f, 0.f, 0.f};

    #pragma unroll
    for (int s = 0; s < 8; ++s){
      const int kk = s * 32 + g * 8;
      bfrag hv = *(const bfrag*)(h1b + (rowt + lr) * 256 + kk);
      bfrag ahi, alo;
      #pragma unroll
      for (int e = 0; e < 8; ++e){
        float x = fmaf(bf16tof((unsigned short)hv[e]), ssl[kk + e], ssl[256 + kk + e]);
        unsigned short h0 = cvt_bf16(x);
        ahi[e] = (short)h0;
        alo[e] = (short)cvt_bf16(x - bf16tof(h0));
      }
      const char* base = (const char*)w2s + s * 4096 + l * 16;
      #pragma unroll
      for (int c = 0; c < 4; ++c){
        const bfrag bhi = *(const bfrag*)(base + c * 1024);
        acc[c] = __builtin_amdgcn_mfma_f32_16x16x32_bf16(ahi, bhi, acc[c], 0, 0, 0);
        acc[c] = __builtin_amdgcn_mfma_f32_16x16x32_bf16(alo, bhi, acc[c], 0, 0, 0);
      }
    }

    #pragma unroll
    for (int c = 0; c < 4; ++c){
      int j = c * 16 + lr;
      float bb = b2[j];
      #pragma unroll
      for (int e = 0; e < 4; ++e){
        float h = acc[c][e] + bb;
        h2l[w][g * 4 + e][j] = h > 0.f ? h : 0.f;
      }
    }

    float a3[4];
    #pragma unroll
    for (int t3 = 0; t3 < 4; ++t3) a3[t3] = b3[g * 4 + t3];
    #pragma unroll 4
    for (int k = 0; k < 64; ++k){
      float hv = h2l[w][lr][k];
      #pragma unroll
      for (int t3 = 0; t3 < 4; ++t3) a3[t3] += hv * W3[(g * 4 + t3) * 64 + k];
    }

    float p = 0.f;
    #pragma unroll
    for (int t3 = 0; t3 < 4; ++t3){
      float h = a3[t3] > 0.f ? a3[t3] : 0.f;
      p += h * W4[g * 4 + t3];
    }
    p += __shfl_xor(p, 16);
    p += __shfl_xor(p, 32);
    if (l < 16) out[rowt + lr] = p + b4v;
  }
}

extern "C" void kernel_launch(void* const* d_in, const int* in_sizes, int n_in,
                              void* d_out, int out_size, void* d_ws, size_t ws_size,
                              hipStream_t stream){
  const int*   state = (const int*)d_in[0];
  const int*   counts= (const int*)d_in[1];
  const int*   mp    = (const int*)d_in[2];
  const float* embed = (const float*)d_in[3];
  const float* stab  = (const float*)d_in[4];
  const float* ctab  = (const float*)d_in[5];
  const float* W1    = (const float*)d_in[6];
  const float* b1    = (const float*)d_in[7];
  const float* gamma = (const float*)d_in[8];
  const float* beta  = (const float*)d_in[9];
  const float* W2    = (const float*)d_in[10];
  const float* b2    = (const float*)d_in[11];
  const float* W3    = (const float*)d_in[12];
  const float* b3    = (const float*)d_in[13];
  const float* W4    = (const float*)d_in[14];
  const float* b4    = (const float*)d_in[15];
  float* out = (float*)d_out;

  char* ws = (char*)d_ws;
  unsigned short* h1bf = (unsigned short*)(ws);              // 32 MiB
  float* gsum          = (float*)(ws + 33554432);            // 2 KiB (sum|sq)
  unsigned short* W1p  = (unsigned short*)(ws + 33558528);   // 224 KiB
  unsigned short* W2p  = (unsigned short*)(ws + 33787904);   // 32 KiB

  k_prep <<<448, 256, 0, stream>>>(W1, W2, W1p, W2p, gsum);
  k_gemm1<<<512, 256, 0, stream>>>(state, counts, mp, embed, stab, ctab,
                                   W1p, b1, h1bf, gsum);
  k_tail <<<512, 256, 0, stream>>>(h1bf, gsum, gamma, beta, W2p,
                                   b2, W3, b3, W4, b4, out);
}